// Round 9
// baseline (1471.025 us; speedup 1.0000x reference)
//
#include <hip/hip_runtime.h>
#include <cstdint>

// ---- problem constants ----
#define B_   256
#define NPOS 196        // 14*14
#define D_   2048
#define H_   1024
#define A_   512
#define T_   10

// W13 = [dec_att_w(512); w_hh(4096); stop_p_w(256); topic_h_w(1024); stop_c_w(256)]
#define N13  6144
#define OFF_DEC    0
#define OFF_WHH    512
#define OFF_STOPP  4608
#define OFF_TOPICH 4864
#define OFF_STOPC  5888
// Wc = [w_ih(4096); topic_c_w(1024)] @ ctx_w   -> [5120 x 2048]
#define NC   5120

#define QMAX 6.5f
#define QSINV (127.f / QMAX)
#define QS    (QMAX / 127.f)

#define PS13 ((size_t)B_ * N13)
#define PSNC ((size_t)B_ * NC)

typedef __attribute__((ext_vector_type(8))) short bf16x8;
typedef __attribute__((ext_vector_type(4))) short bf16x4;
typedef __attribute__((ext_vector_type(4))) float f32x4;

__device__ __forceinline__ float b2f(short s) {
  union { unsigned int u; float f; } c;
  c.u = ((unsigned int)(unsigned short)s) << 16;
  return c.f;
}
__device__ __forceinline__ short f2b(float f) {
  union { float f; unsigned int u; } c; c.f = f;
  unsigned int u = c.u + 0x7fffu + ((c.u >> 16) & 1u);  // RNE
  return (short)(u >> 16);
}
// packed RNE f32x2 -> bf16x2 (same rounding as f2b)
__device__ __forceinline__ unsigned int pk_bf16(float lo, float hi) {
  unsigned int r;
  asm volatile("v_cvt_pk_bf16_f32 %0, %1, %2" : "=v"(r) : "v"(lo), "v"(hi));
  return r;
}
__device__ __forceinline__ float fast_tanh(float x) {
  float a = fabsf(x);
  float e = __expf(-2.f * a);
  float t = __fdividef(1.f - e, 1.f + e);
  return x < 0.f ? -t : t;
}
__device__ __forceinline__ float fast_sigm(float x) {
  return __fdividef(1.f, 1.f + __expf(-x));
}

#define GLDS16(g, l) __builtin_amdgcn_global_load_lds( \
    (const __attribute__((address_space(1))) void*)(g), \
    (__attribute__((address_space(3))) void*)(l), 16, 0, 0)

// ---------------- batched weight cvt: 8 segments ----------------
struct SegTab {
  const float* src[8];
  short* dst[8];
  int cum[9];
};
__global__ __launch_bounds__(256) void cvt_multi_k(SegTab t)
{
  int seg = 0;
  #pragma unroll
  for (int s = 0; s < 7; ++s) seg += (int)(blockIdx.x >= (unsigned)t.cum[s + 1]);
  const long i = ((long)(blockIdx.x - t.cum[seg]) * 256 + threadIdx.x) * 8;
  const float* in = t.src[seg];
  float4 a = *(const float4*)(in + i);
  float4 b = *(const float4*)(in + i + 4);
  bf16x8 o;
  o[0]=f2b(a.x); o[1]=f2b(a.y); o[2]=f2b(a.z); o[3]=f2b(a.w);
  o[4]=f2b(b.x); o[5]=f2b(b.y); o[6]=f2b(b.z); o[7]=f2b(b.w);
  *(bf16x8*)(t.dst[seg] + i) = o;
}

// ---------------- transpose + convert: in[R][C] f32 -> out[C][R] bf16 ----------------
__global__ __launch_bounds__(256) void transpose_cvt_k(
    const float* __restrict__ in, short* __restrict__ out, int R, int C)
{
  __shared__ float t[32][33];
  const int r0 = blockIdx.y * 32, c0 = blockIdx.x * 32;
  const int tx = threadIdx.x & 31, ty = threadIdx.x >> 5;
  #pragma unroll
  for (int i = 0; i < 32; i += 8)
    t[ty + i][tx] = in[(size_t)(r0 + ty + i) * C + c0 + tx];
  __syncthreads();
  #pragma unroll
  for (int i = 0; i < 32; i += 8)
    out[(size_t)(c0 + ty + i) * R + r0 + tx] = f2b(t[tx][ty + i]);
}

// ---------------- bias_c[r] = b[r] + dot(w2[r,:], ctx_b) ----------------
__global__ __launch_bounds__(256) void biasc_k(
    const float* __restrict__ w_ih, const float* __restrict__ b_ih,
    const float* __restrict__ topic_c_w, const float* __restrict__ topic_c_b,
    const float* __restrict__ ctx_b, float* __restrict__ out)
{
  const int r = blockIdx.x * 4 + (threadIdx.x >> 6);
  const int l = threadIdx.x & 63;
  const float* wr; float bb;
  if (r < 4096) { wr = w_ih + (size_t)r * 1024;               bb = b_ih[r]; }
  else          { wr = topic_c_w + (size_t)(r - 4096) * 1024; bb = topic_c_b[r - 4096]; }
  float s = 0.f;
  #pragma unroll
  for (int k = 0; k < 16; ++k) s += wr[l + 64 * k] * ctx_b[l + 64 * k];
  #pragma unroll
  for (int o = 32; o; o >>= 1) s += __shfl_down(s, o);
  if (!l) out[r] = s + bb;
}

// ---------------- assemble bias13 ----------------
__global__ __launch_bounds__(256) void bias13_k(
    const float* __restrict__ dec_att_b, const float* __restrict__ b_hh,
    const float* __restrict__ stop_p_b, const float* __restrict__ topic_h_b,
    const float* __restrict__ stop_c_b, float* __restrict__ bias13)
{
  const int j = blockIdx.x * 256 + threadIdx.x;
  float v;
  if      (j < OFF_WHH)    v = dec_att_b[j];
  else if (j < OFF_STOPP)  v = b_hh[j - OFF_WHH];
  else if (j < OFF_TOPICH) v = stop_p_b[j - OFF_STOPP];
  else if (j < OFF_STOPC)  v = topic_h_b[j - OFF_TOPICH];
  else                     v = stop_c_b[j - OFF_STOPC];
  bias13[j] = v;
}

// ---------------- bf16 MFMA GEMM: C = A[M,K] * B[N,K]^T (+ bias) ----------------
// KZ>1: grid.z = K-chunk; writes f32 partial (no bias) to Cout + z*M*N.
template<int OUTBF16, int BN, int KZ>
__global__ __launch_bounds__(256) void gemm_bt_k(
    const short* __restrict__ Aptr, const short* __restrict__ Bptr,
    const float* __restrict__ bias, void* __restrict__ Cout,
    int M, int N, int K)
{
  constexpr int TOT = 16 + BN / 8;
  constexpr int NW  = BN / 32;
  __shared__ short As[128 * 64];
  __shared__ short Bs[BN * 64];
  const int tid = threadIdx.x;
  const int l = tid & 63, wv = tid >> 6;
  const int wr = wv >> 1, wc = wv & 1;
  const size_t m0 = (size_t)blockIdx.y * 128;
  const size_t n0 = (size_t)blockIdx.x * BN;
  const int srow = l >> 3, scol = (l & 7) * 8;
  const int lr = l & 15, lg = l >> 4;
  const int KC = K / KZ;
  const int kbase = (KZ > 1) ? blockIdx.z * KC : 0;
  const int kend  = kbase + KC;

  f32x4 acc[4][NW];
  #pragma unroll
  for (int i = 0; i < 4; ++i)
    #pragma unroll
    for (int j = 0; j < NW; ++j) acc[i][j] = (f32x4){0.f, 0.f, 0.f, 0.f};

  for (int k0 = kbase; k0 < kend; k0 += 64) {
    #pragma unroll
    for (int i = 0; i < TOT / 4; ++i) {
      const int c = i * 4 + wv;
      if (c < 16) {
        const int row = c * 8 + srow;
        GLDS16(Aptr + (m0 + row) * (size_t)K + k0 + scol, As + c * 512);
      } else {
        const int row = (c - 16) * 8 + srow;
        GLDS16(Bptr + (n0 + row) * (size_t)K + k0 + scol, Bs + (c - 16) * 512);
      }
    }
    __syncthreads();
    #pragma unroll
    for (int kk = 0; kk < 64; kk += 32) {
      bf16x8 af[4], bfr[NW];
      #pragma unroll
      for (int m = 0; m < 4; ++m)
        af[m] = *(const bf16x8*)(As + (wr * 64 + m * 16 + lr) * 64 + kk + lg * 8);
      #pragma unroll
      for (int n = 0; n < NW; ++n)
        bfr[n] = *(const bf16x8*)(Bs + (wc * (BN / 2) + n * 16 + lr) * 64 + kk + lg * 8);
      #pragma unroll
      for (int m = 0; m < 4; ++m)
        #pragma unroll
        for (int n = 0; n < NW; ++n)
          acc[m][n] = __builtin_amdgcn_mfma_f32_16x16x32_bf16(af[m], bfr[n], acc[m][n], 0, 0, 0);
    }
    __syncthreads();
  }

  #pragma unroll
  for (int m = 0; m < 4; ++m) {
    const size_t row = m0 + wr * 64 + m * 16 + lg * 4;
    #pragma unroll
    for (int n = 0; n < NW; ++n) {
      const size_t col = n0 + wc * (BN / 2) + n * 16 + lr;
      if (KZ > 1) {
        float* Cp = (float*)Cout + (size_t)blockIdx.z * M * (size_t)N;
        #pragma unroll
        for (int r = 0; r < 4; ++r)
          Cp[(row + r) * (size_t)N + col] = acc[m][n][r];
      } else {
        const float bv = bias[col];
        #pragma unroll
        for (int r = 0; r < 4; ++r) {
          const float v = acc[m][n][r] + bv;
          if (OUTBF16) ((short*)Cout)[(row + r) * (size_t)N + col] = f2b(v);
          else         ((float*)Cout)[(row + r) * (size_t)N + col] = v;
        }
      }
    }
  }
}

// ---------------- enc_proj GEMM reading fp32 vis directly, + fused int8 quant ------
// C[Mrows,512] = bf16(A_f32) @ encw^T + enc_att_b ; tile 128x128, K=2048,
// grid (4, 392) XCD-swizzled. A: fp32 -> cvt_pk bf16 reg-staged into LDS;
// B: bf16 via global_load_lds. Block with n-slot 0 also writes v8 (u8 quant
// of the raw fp32 it already holds) -> each panel quantized exactly once.
template<int QW>
__global__ __launch_bounds__(256) void encproj_k(
    const float* __restrict__ Afp, const short* __restrict__ Bptr,
    const float* __restrict__ bias, short* __restrict__ Cout,
    unsigned char* __restrict__ v8)
{
  constexpr int K = D_;
  constexpr int N = A_;
  __shared__ short As[128 * 64];
  __shared__ short Bs[128 * 64];
  const int tid = threadIdx.x;
  const int l = tid & 63, wv = tid >> 6;
  const int wr = wv >> 1, wc = wv & 1;
  const int id  = blockIdx.y * 4 + blockIdx.x;
  const int xcd = id & 7, s = id >> 3;          // s in 0..195
  const size_t m0 = (size_t)(xcd * 49 + (s >> 2)) * 128;
  const size_t n0 = (size_t)(s & 3) * 128;
  const bool doq = QW && ((s & 3) == 0);
  const int srow = l >> 3, scol = (l & 7) * 8;  // B staging coords
  const int arow = tid >> 4;                    // A staging: base row, +16/pass
  const int acol = (tid & 15) * 4;              // A staging: float4 col
  const int lr = l & 15, lg = l >> 4;

  f32x4 acc[4][4];
  #pragma unroll
  for (int i = 0; i < 4; ++i)
    #pragma unroll
    for (int j = 0; j < 4; ++j) acc[i][j] = (f32x4){0.f, 0.f, 0.f, 0.f};

  for (int k0 = 0; k0 < K; k0 += 64) {
    // B tile -> LDS (async)
    #pragma unroll
    for (int i = 0; i < 4; ++i) {
      const int c = i * 4 + wv;
      GLDS16(Bptr + (n0 + c * 8 + srow) * (size_t)K + k0 + scol, Bs + c * 512);
    }
    // A tile: 8 passes, 16 rows/pass; fp32 float4 -> 2x cvt_pk -> ds_write 8B
    #pragma unroll
    for (int p = 0; p < 8; ++p) {
      const int row = p * 16 + arow;
      const float4 a = *(const float4*)(Afp + (m0 + row) * (size_t)K + k0 + acol);
      uint2 w;
      w.x = pk_bf16(a.x, a.y);
      w.y = pk_bf16(a.z, a.w);
      *(uint2*)(As + row * 64 + acol) = w;
      if (doq) {
        unsigned int q = 0;
        const float vv[4] = {a.x, a.y, a.z, a.w};
        #pragma unroll
        for (int j = 0; j < 4; ++j) {
          float t = fminf(fmaxf(rintf(vv[j] * QSINV), -127.f), 127.f) + 128.f;
          q |= ((unsigned int)(int)t) << (8 * j);
        }
        *(unsigned int*)(v8 + (m0 + row) * (size_t)K + k0 + acol) = q;
      }
    }
    __syncthreads();
    #pragma unroll
    for (int kk = 0; kk < 64; kk += 32) {
      bf16x8 af[4], bfr[4];
      #pragma unroll
      for (int m = 0; m < 4; ++m)
        af[m] = *(const bf16x8*)(As + (wr * 64 + m * 16 + lr) * 64 + kk + lg * 8);
      #pragma unroll
      for (int n = 0; n < 4; ++n)
        bfr[n] = *(const bf16x8*)(Bs + (wc * 64 + n * 16 + lr) * 64 + kk + lg * 8);
      #pragma unroll
      for (int m = 0; m < 4; ++m)
        #pragma unroll
        for (int n = 0; n < 4; ++n)
          acc[m][n] = __builtin_amdgcn_mfma_f32_16x16x32_bf16(af[m], bfr[n], acc[m][n], 0, 0, 0);
    }
    __syncthreads();
  }

  #pragma unroll
  for (int m = 0; m < 4; ++m) {
    const size_t row = m0 + wr * 64 + m * 16 + lg * 4;
    #pragma unroll
    for (int n = 0; n < 4; ++n) {
      const size_t col = n0 + wc * 64 + n * 16 + lr;
      const float bv = bias[col];
      #pragma unroll
      for (int r = 0; r < 4; ++r)
        Cout[(row + r) * (size_t)N + col] = f2b(acc[m][n][r] + bv);
    }
  }
}

// ---- fused final(t-1) + raw scores(t); grid (2, B), 512 thr; block j owns 98 pos ----
template<int DO_FINAL, int DO_SCORES>
__global__ __launch_bounds__(512) void scores_k(
    const float* __restrict__ pcur, const float* __restrict__ pprev,
    const float* __restrict__ g3p, const float* __restrict__ biasc,
    const float* __restrict__ bias13,
    const short* __restrict__ encp, const float* __restrict__ fullw,
    const float* __restrict__ finw, const float* __restrict__ finb,
    float* __restrict__ scbuf, float* __restrict__ out_t,
    float* __restrict__ out_p, int tprev)
{
  const int j = blockIdx.x, b = blockIdx.y, tid = threadIdx.x;
  const int l = tid & 63, wv = tid >> 6;       // 8 waves
  const size_t b13 = (size_t)b * N13;
  __shared__ float dec_s[A_], fw_s[A_], pp[256];

  if (DO_FINAL) {
    float* ot = out_t + (size_t)b * (T_ * 1024) + (size_t)tprev * 1024;
    const int jj = j * 512 + tid;
    float th = bias13[OFF_TOPICH + jj] + pcur[b13 + OFF_TOPICH + jj]
             + pcur[PS13 + b13 + OFF_TOPICH + jj];
    float tc = biasc[4096 + jj];
    #pragma unroll
    for (int z = 0; z < 4; ++z) tc += g3p[z * PSNC + (size_t)b * NC + 4096 + jj];
    ot[jj] = fast_tanh(th + tc);
    if (j == 0 && tid < 256) {     // stop path on block 0
      float a = bias13[OFF_STOPP + tid] + pprev[b13 + OFF_STOPP + tid]
              + pprev[PS13 + b13 + OFF_STOPP + tid];
      float c = bias13[OFF_STOPC + tid] + pcur[b13 + OFF_STOPC + tid]
              + pcur[PS13 + b13 + OFF_STOPC + tid];
      pp[tid] = fast_tanh(a + c);
    }
  }
  if (DO_SCORES) {
    dec_s[tid] = pcur[b13 + tid] + pcur[PS13 + b13 + tid] + bias13[tid];
    fw_s[tid]  = fullw[tid];
  }
  __syncthreads();

  if (DO_FINAL && j == 0 && wv < 2) {
    float s = 0.f;
    #pragma unroll
    for (int k = 0; k < 4; ++k) s += pp[l + 64 * k] * finw[wv * 256 + l + 64 * k];
    #pragma unroll
    for (int o = 32; o; o >>= 1) s += __shfl_down(s, o);
    if (!l) out_p[(size_t)b * (T_ * 2) + tprev * 2 + wv] = s + finb[wv];
  }

  if (DO_SCORES) {
    // raw logits for positions n = j*98 + [0,98)
    const short* ep = encp + ((size_t)b * NPOS + j * 98) * A_;
    for (int n = wv; n < 98; n += 8) {
      bf16x8 e = *(const bf16x8*)(ep + (size_t)n * A_ + l * 8);
      float s = 0.f;
      #pragma unroll
      for (int k = 0; k < 8; ++k)
        s += fast_tanh(b2f(e[k]) + dec_s[l * 8 + k]) * fw_s[l * 8 + k];
      #pragma unroll
      for (int o = 32; o; o >>= 1) s += __shfl_down(s, o);
      if (!l) scbuf[(size_t)b * NPOS + j * 98 + n] = s;
    }
  }
}

// ---- PV (+inline softmax from raw logits): grid (4, B), 256 thr, 4-way n-split ----
template<int VMODE>   // 1: int8 ws, 0: fp32 vis
__global__ __launch_bounds__(256) void pv_k(
    const void* __restrict__ vptr, const float* __restrict__ scbuf,
    short* __restrict__ attout)
{
  const int b = blockIdx.y;
  const int dbase = blockIdx.x * 512;      // block owns 512 dims
  const int tid = threadIdx.x;
  const int l = tid & 63, grp = tid >> 6;  // grp = n-group 0..3
  __shared__ float sc[NPOS];
  __shared__ float red[8];
  __shared__ float tmp[3][512];

  const float lg = (tid < NPOS) ? scbuf[(size_t)b * NPOS + tid] : -3e38f;
  float lm = lg;
  #pragma unroll
  for (int o = 32; o; o >>= 1) lm = fmaxf(lm, __shfl_down(lm, o));
  if (!l) red[grp] = lm;
  __syncthreads();
  const float mx = fmaxf(fmaxf(red[0], red[1]), fmaxf(red[2], red[3]));
  const float ev = (tid < NPOS) ? __expf(lg - mx) : 0.f;
  float es = ev;
  #pragma unroll
  for (int o = 32; o; o >>= 1) es += __shfl_down(es, o);
  if (!l) red[4 + grp] = es;
  __syncthreads();
  const float inv = __fdividef(1.f, red[4] + red[5] + red[6] + red[7]);
  if (tid < NPOS) sc[tid] = ev * inv;
  __syncthreads();

  const int dt = l * 8;
  float a[8] = {0,0,0,0,0,0,0,0};
  if (VMODE == 1) {
    const unsigned char* vb = (const unsigned char*)vptr
        + (size_t)b * NPOS * D_ + dbase + dt;
    #pragma unroll 7
    for (int n = grp; n < NPOS; n += 4) {
      const float s = sc[n];
      const uint2 w = *(const uint2*)(vb + (size_t)n * D_);
      a[0] += s * (float)(w.x & 255u);
      a[1] += s * (float)((w.x >> 8) & 255u);
      a[2] += s * (float)((w.x >> 16) & 255u);
      a[3] += s * (float)(w.x >> 24);
      a[4] += s * (float)(w.y & 255u);
      a[5] += s * (float)((w.y >> 8) & 255u);
      a[6] += s * (float)((w.y >> 16) & 255u);
      a[7] += s * (float)(w.y >> 24);
    }
  } else {
    const float* vf = (const float*)vptr + (size_t)b * NPOS * D_ + dbase + dt;
    #pragma unroll 2
    for (int n = grp; n < NPOS; n += 4) {
      const float s = sc[n];
      float4 v0 = *(const float4*)(vf + (size_t)n * D_);
      float4 v1 = *(const float4*)(vf + (size_t)n * D_ + 4);
      a[0] += s*v0.x; a[1] += s*v0.y; a[2] += s*v0.z; a[3] += s*v0.w;
      a[4] += s*v1.x; a[5] += s*v1.y; a[6] += s*v1.z; a[7] += s*v1.w;
    }
  }
  if (grp) {
    #pragma unroll
    for (int k = 0; k < 8; ++k) tmp[grp - 1][dt + k] = a[k];
  }
  __syncthreads();
  if (!grp) {
    bf16x8 o8;
    #pragma unroll
    for (int k = 0; k < 8; ++k) {
      float v = a[k] + tmp[0][dt + k] + tmp[1][dt + k] + tmp[2][dt + k];
      if (VMODE == 1) v = v * QS - 128.f * QS;   // sum(sc)=1
      o8[k] = f2b(v);
    }
    *(bf16x8*)(attout + (size_t)b * D_ + dbase + dt) = o8;
  }
}

// ---------------- LSTM cell: sums split-K partials + biases ----------------
__global__ __launch_bounds__(128) void lstm_k(
    const float* __restrict__ g3p, const float* __restrict__ gPp,
    const float* __restrict__ biasc, const float* __restrict__ bias13,
    float* __restrict__ c, short* __restrict__ hbf)
{
  const int idx = (blockIdx.x * 128 + threadIdx.x) * 4;  // 0..B*H-1 step 4
  const int b = idx >> 10, j = idx & 1023;
  f32x4 gate[4];
  #pragma unroll
  for (int g = 0; g < 4; ++g) {
    const size_t base  = (size_t)b * NC + g * 1024 + j;
    const size_t baseh = (size_t)b * N13 + OFF_WHH + g * 1024 + j;
    f32x4 s = *(const f32x4*)(biasc + g * 1024 + j);
    s += *(const f32x4*)(bias13 + OFF_WHH + g * 1024 + j);
    #pragma unroll
    for (int z = 0; z < 4; ++z) s += *(const f32x4*)(g3p + z * PSNC + base);
    #pragma unroll
    for (int z = 0; z < 2; ++z) s += *(const f32x4*)(gPp + z * PS13 + baseh);
    gate[g] = s;
  }
  f32x4 cv = *(const f32x4*)(c + idx);
  f32x4 cn;
  bf16x4 hn;
  #pragma unroll
  for (int k = 0; k < 4; ++k) {
    const float nc2 = fast_sigm(gate[1][k]) * cv[k]
                    + fast_sigm(gate[0][k]) * fast_tanh(gate[2][k]);
    cn[k] = nc2;
    hn[k] = f2b(fast_sigm(gate[3][k]) * fast_tanh(nc2));
  }
  *(f32x4*)(c + idx) = cn;
  *(bf16x4*)(hbf + idx) = hn;
}

// ---------------- host ----------------
extern "C" void kernel_launch(void* const* d_in, const int* in_sizes, int n_in,
                              void* d_out, int out_size, void* d_ws, size_t ws_size,
                              hipStream_t stream)
{
  const float* vis       = (const float*)d_in[0];
  const float* enc_att_w = (const float*)d_in[2];
  const float* enc_att_b = (const float*)d_in[3];
  const float* dec_att_w = (const float*)d_in[4];
  const float* dec_att_b = (const float*)d_in[5];
  const float* full_att_w= (const float*)d_in[6];
  const float* ctx_w     = (const float*)d_in[8];
  const float* ctx_b     = (const float*)d_in[9];
  const float* w_ih      = (const float*)d_in[10];
  const float* b_ih      = (const float*)d_in[11];
  const float* w_hh      = (const float*)d_in[12];
  const float* b_hh      = (const float*)d_in[13];
  const float* topic_h_w = (const float*)d_in[14];
  const float* topic_h_b = (const float*)d_in[15];
  const float* topic_c_w = (const float*)d_in[16];
  const float* topic_c_b = (const float*)d_in[17];
  const float* stop_p_w  = (const float*)d_in[18];
  const float* stop_p_b  = (const float*)d_in[19];
  const float* stop_c_w  = (const float*)d_in[20];
  const float* stop_c_b  = (const float*)d_in[21];
  const float* final_w   = (const float*)d_in[22];
  const float* final_b   = (const float*)d_in[23];

  uint8_t* wsp = (uint8_t*)d_ws;
  size_t off = 0;
  auto take = [&](size_t bytes) -> void* {
    void* p = wsp + off;
    off = (off + bytes + 255) & ~(size_t)255;
    return p;
  };

  short* encproj = (short*)take((size_t)B_ * NPOS * A_ * 2);   // 51.4 MB
  short* encw    = (short*)take((size_t)A_ * D_ * 2);
  short* w2cat   = (short*)take((size_t)NC * 1024 * 2);
  short* ctxwT   = (short*)take((size_t)D_ * 1024 * 2);
  short* Wc      = (short*)take((size_t)NC * D_ * 2);
  short* w13     = (short*)take((size_t)N13 * H_ * 2);
  float* biasc   = (float*)take((size_t)NC * 4);
  float* bias13  = (float*)take((size_t)N13 * 4);
  float* zeros   = (float*)take((size_t)D_ * 4);
  short* hbf     = (short*)take((size_t)B_ * H_ * 2);
  float* cst     = (float*)take((size_t)B_ * H_ * 4);
  float* pairs0  = (float*)take(2 * PS13 * 4);    // 12.6 MB (2 partials)
  float* pairs1  = (float*)take(2 * PS13 * 4);
  float* g3p     = (float*)take(4 * PSNC * 4);    // 21 MB (4 partials)
  short* attb    = (short*)take((size_t)B_ * D_ * 2);
  float* scbuf   = (float*)take((size_t)B_ * NPOS * 4);
  const long nv = (long)B_ * NPOS * D_;
  unsigned char* v8 = (unsigned char*)take((size_t)nv);        // 102.8 MB int8
  const bool full = (ws_size >= off);                          // v8 fits?

  float* out_t = (float*)d_out;
  float* out_p = (float*)d_out + (size_t)B_ * T_ * 1024;

  // ---- one-time weight prep ----
  {
    SegTab t;
    const float* srcs[8] = {enc_att_w, w_ih, topic_c_w, dec_att_w, w_hh,
                            stop_p_w, topic_h_w, stop_c_w};
    short* dsts[8] = {encw, w2cat, w2cat + (size_t)4096 * 1024,
                      w13 + (size_t)OFF_DEC * 1024, w13 + (size_t)OFF_WHH * 1024,
                      w13 + (size_t)OFF_STOPP * 1024, w13 + (size_t)OFF_TOPICH * 1024,
                      w13 + (size_t)OFF_STOPC * 1024};
    const int nel[8] = {1048576, 4194304, 1048576, 524288, 4194304, 262144, 1048576, 262144};
    int c = 0;
    for (int i = 0; i < 8; ++i) {
      t.src[i] = srcs[i]; t.dst[i] = dsts[i];
      t.cum[i] = c; c += nel[i] / 2048;
    }
    t.cum[8] = c;
    cvt_multi_k<<<c, 256, 0, stream>>>(t);
  }
  transpose_cvt_k<<<dim3(D_ / 32, 1024 / 32), 256, 0, stream>>>(ctx_w, ctxwT, 1024, D_);
  hipMemsetAsync(zeros, 0, (size_t)D_ * 4, stream);
  gemm_bt_k<1, 128, 1><<<dim3(D_ / 128, NC / 128), 256, 0, stream>>>(
      w2cat, ctxwT, zeros, Wc, NC, D_, 1024);
  biasc_k<<<NC / 4, 256, 0, stream>>>(w_ih, b_ih, topic_c_w, topic_c_b, ctx_b, biasc);
  bias13_k<<<N13 / 256, 256, 0, stream>>>(
      dec_att_b, b_hh, stop_p_b, topic_h_b, stop_c_b, bias13);
  hipMemsetAsync(cst, 0, (size_t)B_ * H_ * 4, stream);
  hipMemsetAsync(pairs1, 0, 2 * PS13 * 4, stream);   // pair(-1) = 0 (h0 = 0)

  // ---- enc_proj straight from fp32 vis (+fused int8 quant of v) ----
  if (full)
    encproj_k<1><<<dim3(4, 392), 256, 0, stream>>>(vis, encw, enc_att_b, encproj, v8);
  else
    encproj_k<0><<<dim3(4, 392), 256, 0, stream>>>(vis, encw, enc_att_b, encproj, nullptr);

  // ---- sequential sentence-LSTM steps (5 kernels/step) ----
  // pair(t) = (t&1) ? pairs1 : pairs0 ; pair(-1) = pairs1 (zeroed)
  for (int t = 0; t < T_; ++t) {
    float* pcur  = (t & 1) ? pairs0 : pairs1;   // pair(t-1)
    float* pprev = (t & 1) ? pairs1 : pairs0;   // pair(t-2)
    if (t == 0)
      scores_k<0, 1><<<dim3(2, B_), 512, 0, stream>>>(pcur, pprev, g3p, biasc, bias13,
          encproj, full_att_w, final_w, final_b, scbuf, out_t, out_p, 0);
    else
      scores_k<1, 1><<<dim3(2, B_), 512, 0, stream>>>(pcur, pprev, g3p, biasc, bias13,
          encproj, full_att_w, final_w, final_b, scbuf, out_t, out_p, t - 1);
    if (full) pv_k<1><<<dim3(4, B_), 256, 0, stream>>>(v8, scbuf, attb);
    else      pv_k<0><<<dim3(4, B_), 256, 0, stream>>>(vis, scbuf, attb);
    // g3 partials: att_out @ Wc^T, split-K 4, BN=128
    gemm_bt_k<0, 128, 4><<<dim3(NC / 128, B_ / 128, 4), 256, 0, stream>>>(
        attb, Wc, nullptr, g3p, B_, NC, D_);
    lstm_k<<<(B_ * H_) / 512, 128, 0, stream>>>(g3p, pcur, biasc, bias13, cst, hbf);
    // pair(t) partials: h_new @ W13^T, split-K 2, BN=64
    float* pnew = (t & 1) ? pairs1 : pairs0;
    gemm_bt_k<0, 64, 2><<<dim3(N13 / 64, B_ / 128, 2), 256, 0, stream>>>(
        hbf, w13, nullptr, pnew, B_, N13, H_);
  }
  // tail: final(T-1)
  {
    float* pcur  = ((T_ - 1) & 1) ? pairs1 : pairs0;  // pair(9)
    float* pprev = ((T_ - 1) & 1) ? pairs0 : pairs1;  // pair(8)
    scores_k<1, 0><<<dim3(2, B_), 512, 0, stream>>>(pcur, pprev, g3p, biasc, bias13,
        encproj, full_att_w, final_w, final_b, scbuf, out_t, out_p, T_ - 1);
  }
}

// Round 10
// 1119.226 us; speedup vs baseline: 1.3143x; 1.3143x over previous
//
#include <hip/hip_runtime.h>
#include <cstdint>

// ---- problem constants ----
#define B_   256
#define NPOS 196        // 14*14
#define D_   2048
#define H_   1024
#define A_   512
#define T_   10

// W13 = [dec_att_w(512); w_hh(4096); stop_p_w(256); topic_h_w(1024); stop_c_w(256)]
#define N13  6144
#define OFF_DEC    0
#define OFF_WHH    512
#define OFF_STOPP  4608
#define OFF_TOPICH 4864
#define OFF_STOPC  5888
// Wc = [w_ih(4096); topic_c_w(1024)] @ ctx_w   -> [5120 x 2048]
#define NC   5120

#define QMAX 6.5f
#define QSINV (127.f / QMAX)
#define QS    (QMAX / 127.f)

#define PS13 ((size_t)B_ * N13)
#define PSNC ((size_t)B_ * NC)

typedef __attribute__((ext_vector_type(8))) short bf16x8;
typedef __attribute__((ext_vector_type(4))) short bf16x4;
typedef __attribute__((ext_vector_type(4))) float f32x4;

__device__ __forceinline__ float b2f(short s) {
  union { unsigned int u; float f; } c;
  c.u = ((unsigned int)(unsigned short)s) << 16;
  return c.f;
}
__device__ __forceinline__ short f2b(float f) {
  union { float f; unsigned int u; } c; c.f = f;
  unsigned int u = c.u + 0x7fffu + ((c.u >> 16) & 1u);  // RNE
  return (short)(u >> 16);
}
__device__ __forceinline__ float fast_tanh(float x) {
  float a = fabsf(x);
  float e = __expf(-2.f * a);
  float t = __fdividef(1.f - e, 1.f + e);
  return x < 0.f ? -t : t;
}
__device__ __forceinline__ float fast_sigm(float x) {
  return __fdividef(1.f, 1.f + __expf(-x));
}

#define GLDS16(g, l) __builtin_amdgcn_global_load_lds( \
    (const __attribute__((address_space(1))) void*)(g), \
    (__attribute__((address_space(3))) void*)(l), 16, 0, 0)

// ---------------- fused: vis f32 -> v16 bf16 + v8 u8 (fixed scale) ----------------
__global__ __launch_bounds__(256) void cvtq_v_k(
    const float* __restrict__ in, short* __restrict__ v16,
    unsigned char* __restrict__ v8, long n)
{
  long i = ((long)blockIdx.x * blockDim.x + threadIdx.x) * 8;
  const long stride = (long)gridDim.x * blockDim.x * 8;
  for (; i < n; i += stride) {
    float4 a = *(const float4*)(in + i);
    float4 b = *(const float4*)(in + i + 4);
    bf16x8 o;
    o[0]=f2b(a.x); o[1]=f2b(a.y); o[2]=f2b(a.z); o[3]=f2b(a.w);
    o[4]=f2b(b.x); o[5]=f2b(b.y); o[6]=f2b(b.z); o[7]=f2b(b.w);
    *(bf16x8*)(v16 + i) = o;
    float v[8] = {a.x,a.y,a.z,a.w,b.x,b.y,b.z,b.w};
    unsigned int w0 = 0, w1 = 0;
    #pragma unroll
    for (int j = 0; j < 4; ++j) {
      float q = fminf(fmaxf(rintf(v[j] * QSINV), -127.f), 127.f) + 128.f;
      w0 |= ((unsigned int)(int)q) << (8 * j);
    }
    #pragma unroll
    for (int j = 0; j < 4; ++j) {
      float q = fminf(fmaxf(rintf(v[4+j] * QSINV), -127.f), 127.f) + 128.f;
      w1 |= ((unsigned int)(int)q) << (8 * j);
    }
    uint2 pk; pk.x = w0; pk.y = w1;
    *(uint2*)(v8 + i) = pk;
  }
}

// ---------------- plain fp32 -> bf16 (chunked fallback path) ----------------
__global__ void cvt_k(const float* __restrict__ in, short* __restrict__ out, long n)
{
  long i = ((long)blockIdx.x * blockDim.x + threadIdx.x) * 8;
  const long stride = (long)gridDim.x * blockDim.x * 8;
  for (; i < n; i += stride) {
    float4 a = *(const float4*)(in + i);
    float4 b = *(const float4*)(in + i + 4);
    bf16x8 o;
    o[0]=f2b(a.x); o[1]=f2b(a.y); o[2]=f2b(a.z); o[3]=f2b(a.w);
    o[4]=f2b(b.x); o[5]=f2b(b.y); o[6]=f2b(b.z); o[7]=f2b(b.w);
    *(bf16x8*)(out + i) = o;
  }
}

// ---------------- batched weight cvt: 8 segments ----------------
struct SegTab {
  const float* src[8];
  short* dst[8];
  int cum[9];
};
__global__ __launch_bounds__(256) void cvt_multi_k(SegTab t)
{
  int seg = 0;
  #pragma unroll
  for (int s = 0; s < 7; ++s) seg += (int)(blockIdx.x >= (unsigned)t.cum[s + 1]);
  const long i = ((long)(blockIdx.x - t.cum[seg]) * 256 + threadIdx.x) * 8;
  const float* in = t.src[seg];
  float4 a = *(const float4*)(in + i);
  float4 b = *(const float4*)(in + i + 4);
  bf16x8 o;
  o[0]=f2b(a.x); o[1]=f2b(a.y); o[2]=f2b(a.z); o[3]=f2b(a.w);
  o[4]=f2b(b.x); o[5]=f2b(b.y); o[6]=f2b(b.z); o[7]=f2b(b.w);
  *(bf16x8*)(t.dst[seg] + i) = o;
}

// ---------------- transpose + convert: in[R][C] f32 -> out[C][R] bf16 ----------------
__global__ __launch_bounds__(256) void transpose_cvt_k(
    const float* __restrict__ in, short* __restrict__ out, int R, int C)
{
  __shared__ float t[32][33];
  const int r0 = blockIdx.y * 32, c0 = blockIdx.x * 32;
  const int tx = threadIdx.x & 31, ty = threadIdx.x >> 5;
  #pragma unroll
  for (int i = 0; i < 32; i += 8)
    t[ty + i][tx] = in[(size_t)(r0 + ty + i) * C + c0 + tx];
  __syncthreads();
  #pragma unroll
  for (int i = 0; i < 32; i += 8)
    out[(size_t)(c0 + ty + i) * R + r0 + tx] = f2b(t[tx][ty + i]);
}

// ---------------- bias_c[r] = b[r] + dot(w2[r,:], ctx_b) ----------------
__global__ __launch_bounds__(256) void biasc_k(
    const float* __restrict__ w_ih, const float* __restrict__ b_ih,
    const float* __restrict__ topic_c_w, const float* __restrict__ topic_c_b,
    const float* __restrict__ ctx_b, float* __restrict__ out)
{
  const int r = blockIdx.x * 4 + (threadIdx.x >> 6);
  const int l = threadIdx.x & 63;
  const float* wr; float bb;
  if (r < 4096) { wr = w_ih + (size_t)r * 1024;               bb = b_ih[r]; }
  else          { wr = topic_c_w + (size_t)(r - 4096) * 1024; bb = topic_c_b[r - 4096]; }
  float s = 0.f;
  #pragma unroll
  for (int k = 0; k < 16; ++k) s += wr[l + 64 * k] * ctx_b[l + 64 * k];
  #pragma unroll
  for (int o = 32; o; o >>= 1) s += __shfl_down(s, o);
  if (!l) out[r] = s + bb;
}

// ---------------- assemble bias13 ----------------
__global__ __launch_bounds__(256) void bias13_k(
    const float* __restrict__ dec_att_b, const float* __restrict__ b_hh,
    const float* __restrict__ stop_p_b, const float* __restrict__ topic_h_b,
    const float* __restrict__ stop_c_b, float* __restrict__ bias13)
{
  const int j = blockIdx.x * 256 + threadIdx.x;
  float v;
  if      (j < OFF_WHH)    v = dec_att_b[j];
  else if (j < OFF_STOPP)  v = b_hh[j - OFF_WHH];
  else if (j < OFF_TOPICH) v = stop_p_b[j - OFF_STOPP];
  else if (j < OFF_STOPC)  v = topic_h_b[j - OFF_TOPICH];
  else                     v = stop_c_b[j - OFF_STOPC];
  bias13[j] = v;
}

// ---------------- bf16 MFMA GEMM: C = A[M,K] * B[N,K]^T (+ bias) ----------------
// KZ>1: grid.z = K-chunk; writes f32 partial (no bias) to Cout + z*M*N.
template<int OUTBF16, int BN, int SWZ, int KZ>
__global__ __launch_bounds__(256) void gemm_bt_k(
    const short* __restrict__ Aptr, const short* __restrict__ Bptr,
    const float* __restrict__ bias, void* __restrict__ Cout,
    int M, int N, int K)
{
  constexpr int TOT = 16 + BN / 8;
  constexpr int NW  = BN / 32;
  __shared__ short As[128 * 64];
  __shared__ short Bs[BN * 64];
  const int tid = threadIdx.x;
  const int l = tid & 63, wv = tid >> 6;
  const int wr = wv >> 1, wc = wv & 1;
  size_t m0, n0;
  if (SWZ) {  // grid (4, 392): A-panel blocks -> same XCD
    const int id  = blockIdx.y * 4 + blockIdx.x;
    const int xcd = id & 7, s = id >> 3;
    m0 = (size_t)(xcd * 49 + (s >> 2)) * 128;
    n0 = (size_t)(s & 3) * BN;
  } else {
    m0 = (size_t)blockIdx.y * 128;
    n0 = (size_t)blockIdx.x * BN;
  }
  const int srow = l >> 3, scol = (l & 7) * 8;
  const int lr = l & 15, lg = l >> 4;
  const int KC = K / KZ;
  const int kbase = (KZ > 1) ? blockIdx.z * KC : 0;
  const int kend  = kbase + KC;

  f32x4 acc[4][NW];
  #pragma unroll
  for (int i = 0; i < 4; ++i)
    #pragma unroll
    for (int j = 0; j < NW; ++j) acc[i][j] = (f32x4){0.f, 0.f, 0.f, 0.f};

  for (int k0 = kbase; k0 < kend; k0 += 64) {
    #pragma unroll
    for (int i = 0; i < TOT / 4; ++i) {
      const int c = i * 4 + wv;
      if (c < 16) {
        const int row = c * 8 + srow;
        GLDS16(Aptr + (m0 + row) * (size_t)K + k0 + scol, As + c * 512);
      } else {
        const int row = (c - 16) * 8 + srow;
        GLDS16(Bptr + (n0 + row) * (size_t)K + k0 + scol, Bs + (c - 16) * 512);
      }
    }
    __syncthreads();
    #pragma unroll
    for (int kk = 0; kk < 64; kk += 32) {
      bf16x8 af[4], bfr[NW];
      #pragma unroll
      for (int m = 0; m < 4; ++m)
        af[m] = *(const bf16x8*)(As + (wr * 64 + m * 16 + lr) * 64 + kk + lg * 8);
      #pragma unroll
      for (int n = 0; n < NW; ++n)
        bfr[n] = *(const bf16x8*)(Bs + (wc * (BN / 2) + n * 16 + lr) * 64 + kk + lg * 8);
      #pragma unroll
      for (int m = 0; m < 4; ++m)
        #pragma unroll
        for (int n = 0; n < NW; ++n)
          acc[m][n] = __builtin_amdgcn_mfma_f32_16x16x32_bf16(af[m], bfr[n], acc[m][n], 0, 0, 0);
    }
    __syncthreads();
  }

  #pragma unroll
  for (int m = 0; m < 4; ++m) {
    const size_t row = m0 + wr * 64 + m * 16 + lg * 4;
    #pragma unroll
    for (int n = 0; n < NW; ++n) {
      const size_t col = n0 + wc * (BN / 2) + n * 16 + lr;
      if (KZ > 1) {
        float* Cp = (float*)Cout + (size_t)blockIdx.z * M * (size_t)N;
        #pragma unroll
        for (int r = 0; r < 4; ++r)
          Cp[(row + r) * (size_t)N + col] = acc[m][n][r];
      } else {
        const float bv = bias[col];
        #pragma unroll
        for (int r = 0; r < 4; ++r) {
          const float v = acc[m][n][r] + bv;
          if (OUTBF16) ((short*)Cout)[(row + r) * (size_t)N + col] = f2b(v);
          else         ((float*)Cout)[(row + r) * (size_t)N + col] = v;
        }
      }
    }
  }
}

// ---- fused final(t-1) + raw scores(t); grid (2, B), 512 thr; block j owns 98 pos ----
template<int DO_FINAL, int DO_SCORES>
__global__ __launch_bounds__(512) void scores_k(
    const float* __restrict__ pcur, const float* __restrict__ pprev,
    const float* __restrict__ g3p, const float* __restrict__ biasc,
    const float* __restrict__ bias13,
    const short* __restrict__ encp, const float* __restrict__ fullw,
    const float* __restrict__ finw, const float* __restrict__ finb,
    float* __restrict__ scbuf, float* __restrict__ out_t,
    float* __restrict__ out_p, int tprev)
{
  const int j = blockIdx.x, b = blockIdx.y, tid = threadIdx.x;
  const int l = tid & 63, wv = tid >> 6;       // 8 waves
  const size_t b13 = (size_t)b * N13;
  __shared__ float dec_s[A_], fw_s[A_], pp[256];

  if (DO_FINAL) {
    // topic(t-1): block j writes elems [j*512, j*512+512)
    float* ot = out_t + (size_t)b * (T_ * 1024) + (size_t)tprev * 1024;
    const int jj = j * 512 + tid;
    float th = bias13[OFF_TOPICH + jj] + pcur[b13 + OFF_TOPICH + jj]
             + pcur[PS13 + b13 + OFF_TOPICH + jj];
    float tc = biasc[4096 + jj];
    #pragma unroll
    for (int z = 0; z < 4; ++z) tc += g3p[z * PSNC + (size_t)b * NC + 4096 + jj];
    ot[jj] = fast_tanh(th + tc);
    if (j == 0 && tid < 256) {     // stop path on block 0
      float a = bias13[OFF_STOPP + tid] + pprev[b13 + OFF_STOPP + tid]
              + pprev[PS13 + b13 + OFF_STOPP + tid];
      float c = bias13[OFF_STOPC + tid] + pcur[b13 + OFF_STOPC + tid]
              + pcur[PS13 + b13 + OFF_STOPC + tid];
      pp[tid] = fast_tanh(a + c);
    }
  }
  if (DO_SCORES) {
    dec_s[tid] = pcur[b13 + tid] + pcur[PS13 + b13 + tid] + bias13[tid];
    fw_s[tid]  = fullw[tid];
  }
  __syncthreads();

  if (DO_FINAL && j == 0 && wv < 2) {
    float s = 0.f;
    #pragma unroll
    for (int k = 0; k < 4; ++k) s += pp[l + 64 * k] * finw[wv * 256 + l + 64 * k];
    #pragma unroll
    for (int o = 32; o; o >>= 1) s += __shfl_down(s, o);
    if (!l) out_p[(size_t)b * (T_ * 2) + tprev * 2 + wv] = s + finb[wv];
  }

  if (DO_SCORES) {
    // raw logits for positions n = j*98 + [0,98)
    const short* ep = encp + ((size_t)b * NPOS + j * 98) * A_;
    for (int n = wv; n < 98; n += 8) {
      bf16x8 e = *(const bf16x8*)(ep + (size_t)n * A_ + l * 8);
      float s = 0.f;
      #pragma unroll
      for (int k = 0; k < 8; ++k)
        s += fast_tanh(b2f(e[k]) + dec_s[l * 8 + k]) * fw_s[l * 8 + k];
      #pragma unroll
      for (int o = 32; o; o >>= 1) s += __shfl_down(s, o);
      if (!l) scbuf[(size_t)b * NPOS + j * 98 + n] = s;
    }
  }
}

// ---- PV (+inline softmax from raw logits): grid (2, B), 256 thr ----
template<int VMODE>   // 1: int8 ws, 0: fp32 vis
__global__ __launch_bounds__(256) void pv_k(
    const void* __restrict__ vptr, const float* __restrict__ scbuf,
    short* __restrict__ attout)
{
  const int b = blockIdx.y;
  const int dbase = blockIdx.x * 1024;
  const int tid = threadIdx.x;
  const int l = tid & 63, wvq = tid >> 6;   // 4 waves
  __shared__ float sc[NPOS];
  __shared__ float red[8];
  __shared__ float tmp[1024];

  // softmax over 196 raw logits (redundant per block; trivial cost)
  const float lg = (tid < NPOS) ? scbuf[(size_t)b * NPOS + tid] : -3e38f;
  float lm = lg;
  #pragma unroll
  for (int o = 32; o; o >>= 1) lm = fmaxf(lm, __shfl_down(lm, o));
  if (!l) red[wvq] = lm;
  __syncthreads();
  const float mx = fmaxf(fmaxf(red[0], red[1]), fmaxf(red[2], red[3]));
  const float ev = (tid < NPOS) ? __expf(lg - mx) : 0.f;
  float es = ev;
  #pragma unroll
  for (int o = 32; o; o >>= 1) es += __shfl_down(es, o);
  if (!l) red[4 + wvq] = es;
  __syncthreads();
  const float inv = __fdividef(1.f, red[4] + red[5] + red[6] + red[7]);
  if (tid < NPOS) sc[tid] = ev * inv;
  __syncthreads();

  // PV: thread owns 8 dims at dbase + (tid&127)*8; 2-way n split (grp)
  const int grp = tid >> 7;
  const int dt = (tid & 127) * 8;
  float a[8] = {0,0,0,0,0,0,0,0};
  if (VMODE == 1) {
    const unsigned char* vb = (const unsigned char*)vptr
        + (size_t)b * NPOS * D_ + dbase + dt;
    #pragma unroll 8
    for (int n = grp; n < NPOS; n += 2) {
      const float s = sc[n];
      const uint2 w = *(const uint2*)(vb + (size_t)n * D_);
      a[0] += s * (float)(w.x & 255u);
      a[1] += s * (float)((w.x >> 8) & 255u);
      a[2] += s * (float)((w.x >> 16) & 255u);
      a[3] += s * (float)(w.x >> 24);
      a[4] += s * (float)(w.y & 255u);
      a[5] += s * (float)((w.y >> 8) & 255u);
      a[6] += s * (float)((w.y >> 16) & 255u);
      a[7] += s * (float)(w.y >> 24);
    }
  } else {
    const float* vf = (const float*)vptr + (size_t)b * NPOS * D_ + dbase + dt;
    #pragma unroll 2
    for (int n = grp; n < NPOS; n += 2) {
      const float s = sc[n];
      float4 v0 = *(const float4*)(vf + (size_t)n * D_);
      float4 v1 = *(const float4*)(vf + (size_t)n * D_ + 4);
      a[0] += s*v0.x; a[1] += s*v0.y; a[2] += s*v0.z; a[3] += s*v0.w;
      a[4] += s*v1.x; a[5] += s*v1.y; a[6] += s*v1.z; a[7] += s*v1.w;
    }
  }
  if (grp == 1) {
    #pragma unroll
    for (int k = 0; k < 8; ++k) tmp[dt + k] = a[k];
  }
  __syncthreads();
  if (grp == 0) {
    bf16x8 o8;
    #pragma unroll
    for (int k = 0; k < 8; ++k) {
      float v = a[k] + tmp[dt + k];
      if (VMODE == 1) v = v * QS - 128.f * QS;   // sum(sc)=1
      o8[k] = f2b(v);
    }
    *(bf16x8*)(attout + (size_t)b * D_ + dbase + dt) = o8;
  }
}

// ---------------- LSTM cell: sums split-K partials + biases ----------------
__global__ __launch_bounds__(128) void lstm_k(
    const float* __restrict__ g3p, const float* __restrict__ gPp,
    const float* __restrict__ biasc, const float* __restrict__ bias13,
    float* __restrict__ c, short* __restrict__ hbf)
{
  const int idx = (blockIdx.x * 128 + threadIdx.x) * 4;  // 0..B*H-1 step 4
  const int b = idx >> 10, j = idx & 1023;
  f32x4 gate[4];
  #pragma unroll
  for (int g = 0; g < 4; ++g) {
    const size_t base  = (size_t)b * NC + g * 1024 + j;
    const size_t baseh = (size_t)b * N13 + OFF_WHH + g * 1024 + j;
    f32x4 s = *(const f32x4*)(biasc + g * 1024 + j);
    s += *(const f32x4*)(bias13 + OFF_WHH + g * 1024 + j);
    #pragma unroll
    for (int z = 0; z < 4; ++z) s += *(const f32x4*)(g3p + z * PSNC + base);
    #pragma unroll
    for (int z = 0; z < 2; ++z) s += *(const f32x4*)(gPp + z * PS13 + baseh);
    gate[g] = s;
  }
  f32x4 cv = *(const f32x4*)(c + idx);
  f32x4 cn;
  bf16x4 hn;
  #pragma unroll
  for (int k = 0; k < 4; ++k) {
    const float nc2 = fast_sigm(gate[1][k]) * cv[k]
                    + fast_sigm(gate[0][k]) * fast_tanh(gate[2][k]);
    cn[k] = nc2;
    hn[k] = f2b(fast_sigm(gate[3][k]) * fast_tanh(nc2));
  }
  *(f32x4*)(c + idx) = cn;
  *(bf16x4*)(hbf + idx) = hn;
}

// ---------------- host ----------------
extern "C" void kernel_launch(void* const* d_in, const int* in_sizes, int n_in,
                              void* d_out, int out_size, void* d_ws, size_t ws_size,
                              hipStream_t stream)
{
  const float* vis       = (const float*)d_in[0];
  const float* enc_att_w = (const float*)d_in[2];
  const float* enc_att_b = (const float*)d_in[3];
  const float* dec_att_w = (const float*)d_in[4];
  const float* dec_att_b = (const float*)d_in[5];
  const float* full_att_w= (const float*)d_in[6];
  const float* ctx_w     = (const float*)d_in[8];
  const float* ctx_b     = (const float*)d_in[9];
  const float* w_ih      = (const float*)d_in[10];
  const float* b_ih      = (const float*)d_in[11];
  const float* w_hh      = (const float*)d_in[12];
  const float* b_hh      = (const float*)d_in[13];
  const float* topic_h_w = (const float*)d_in[14];
  const float* topic_h_b = (const float*)d_in[15];
  const float* topic_c_w = (const float*)d_in[16];
  const float* topic_c_b = (const float*)d_in[17];
  const float* stop_p_w  = (const float*)d_in[18];
  const float* stop_p_b  = (const float*)d_in[19];
  const float* stop_c_w  = (const float*)d_in[20];
  const float* stop_c_b  = (const float*)d_in[21];
  const float* final_w   = (const float*)d_in[22];
  const float* final_b   = (const float*)d_in[23];

  uint8_t* wsp = (uint8_t*)d_ws;
  size_t off = 0;
  auto take = [&](size_t bytes) -> void* {
    void* p = wsp + off;
    off = (off + bytes + 255) & ~(size_t)255;
    return p;
  };

  short* encproj = (short*)take((size_t)B_ * NPOS * A_ * 2);   // 51.4 MB
  short* encw    = (short*)take((size_t)A_ * D_ * 2);
  short* w2cat   = (short*)take((size_t)NC * 1024 * 2);
  short* ctxwT   = (short*)take((size_t)D_ * 1024 * 2);
  short* Wc      = (short*)take((size_t)NC * D_ * 2);
  short* w13     = (short*)take((size_t)N13 * H_ * 2);
  float* biasc   = (float*)take((size_t)NC * 4);
  float* bias13  = (float*)take((size_t)N13 * 4);
  float* zeros   = (float*)take((size_t)D_ * 4);
  short* hbf     = (short*)take((size_t)B_ * H_ * 2);
  float* cst     = (float*)take((size_t)B_ * H_ * 4);
  float* pairs0  = (float*)take(2 * PS13 * 4);    // 12.6 MB (2 partials)
  float* pairs1  = (float*)take(2 * PS13 * 4);
  float* g3p     = (float*)take(4 * PSNC * 4);    // 21 MB (4 partials)
  short* attb    = (short*)take((size_t)B_ * D_ * 2);
  float* scbuf   = (float*)take((size_t)B_ * NPOS * 4);
  const size_t base0 = off;                                    // fallback chunk area
  const long   nv = (long)B_ * NPOS * D_;
  unsigned char* v8 = (unsigned char*)take((size_t)nv);        // 102.8 MB int8
  short* v16 = (short*)(wsp + off);
  const bool full = (ws_size >= off + (size_t)nv * 2);

  float* out_t = (float*)d_out;
  float* out_p = (float*)d_out + (size_t)B_ * T_ * 1024;

  // ---- one-time weight prep ----
  {
    SegTab t;
    const float* srcs[8] = {enc_att_w, w_ih, topic_c_w, dec_att_w, w_hh,
                            stop_p_w, topic_h_w, stop_c_w};
    short* dsts[8] = {encw, w2cat, w2cat + (size_t)4096 * 1024,
                      w13 + (size_t)OFF_DEC * 1024, w13 + (size_t)OFF_WHH * 1024,
                      w13 + (size_t)OFF_STOPP * 1024, w13 + (size_t)OFF_TOPICH * 1024,
                      w13 + (size_t)OFF_STOPC * 1024};
    const int nel[8] = {1048576, 4194304, 1048576, 524288, 4194304, 262144, 1048576, 262144};
    int c = 0;
    for (int i = 0; i < 8; ++i) {
      t.src[i] = srcs[i]; t.dst[i] = dsts[i];
      t.cum[i] = c; c += nel[i] / 2048;
    }
    t.cum[8] = c;
    cvt_multi_k<<<c, 256, 0, stream>>>(t);
  }
  transpose_cvt_k<<<dim3(D_ / 32, 1024 / 32), 256, 0, stream>>>(ctx_w, ctxwT, 1024, D_);
  hipMemsetAsync(zeros, 0, (size_t)D_ * 4, stream);
  gemm_bt_k<1, 128, 0, 1><<<dim3(D_ / 128, NC / 128), 256, 0, stream>>>(
      w2cat, ctxwT, zeros, Wc, NC, D_, 1024);
  biasc_k<<<NC / 4, 256, 0, stream>>>(w_ih, b_ih, topic_c_w, topic_c_b, ctx_b, biasc);
  bias13_k<<<N13 / 256, 256, 0, stream>>>(
      dec_att_b, b_hh, stop_p_b, topic_h_b, stop_c_b, bias13);
  hipMemsetAsync(cst, 0, (size_t)B_ * H_ * 4, stream);
  hipMemsetAsync(pairs1, 0, 2 * PS13 * 4, stream);   // pair(-1) = 0 (h0 = 0)

  // ---- enc_proj = v @ enc_att_w^T + b ; v -> bf16 + int8 ----
  const int Mrows = B_ * NPOS;  // 50176 = 392*128
  if (full) {
    cvtq_v_k<<<8192, 256, 0, stream>>>(vis, v16, v8, nv);
    gemm_bt_k<1, 128, 1, 1><<<dim3(A_ / 128, Mrows / 128), 256, 0, stream>>>(
        v16, encw, enc_att_b, encproj, Mrows, A_, D_);
  } else {
    const size_t avail = (ws_size > base0) ? ws_size - base0 : 0;
    int dt = 1;
    const int cand[] = {56, 28, 14, 8, 7, 4, 2, 1};
    for (int c : cand)
      if ((392 % c) == 0 && (size_t)c * 128 * D_ * 2 <= avail) { dt = c; break; }
    short* vchunk = (short*)(wsp + base0);
    const int CR = dt * 128;
    for (int s = 0; s < Mrows; s += CR) {
      cvt_k<<<4096, 256, 0, stream>>>(vis + (size_t)s * D_, vchunk, (long)CR * D_);
      gemm_bt_k<1, 128, 0, 1><<<dim3(A_ / 128, dt), 256, 0, stream>>>(
          vchunk, encw, enc_att_b, encproj + (size_t)s * A_, CR, A_, D_);
    }
  }

  // ---- sequential sentence-LSTM steps (5 kernels/step) ----
  // pair(t) = (t&1) ? pairs1 : pairs0 ; pair(-1) = pairs1 (zeroed)
  for (int t = 0; t < T_; ++t) {
    float* pcur  = (t & 1) ? pairs0 : pairs1;   // pair(t-1)
    float* pprev = (t & 1) ? pairs1 : pairs0;   // pair(t-2)
    if (t == 0)
      scores_k<0, 1><<<dim3(2, B_), 512, 0, stream>>>(pcur, pprev, g3p, biasc, bias13,
          encproj, full_att_w, final_w, final_b, scbuf, out_t, out_p, 0);
    else
      scores_k<1, 1><<<dim3(2, B_), 512, 0, stream>>>(pcur, pprev, g3p, biasc, bias13,
          encproj, full_att_w, final_w, final_b, scbuf, out_t, out_p, t - 1);
    if (full) pv_k<1><<<dim3(2, B_), 256, 0, stream>>>(v8, scbuf, attb);
    else      pv_k<0><<<dim3(2, B_), 256, 0, stream>>>(vis, scbuf, attb);
    // g3 partials: att_out @ Wc^T, split-K 4, BN=64
    gemm_bt_k<0, 64, 0, 4><<<dim3(NC / 64, B_ / 128, 4), 256, 0, stream>>>(
        attb, Wc, nullptr, g3p, B_, NC, D_);
    lstm_k<<<(B_ * H_) / 512, 128, 0, stream>>>(g3p, pcur, biasc, bias13, cst, hbf);
    // pair(t) partials: h_new @ W13^T, split-K 2, BN=64
    float* pnew = (t & 1) ? pairs1 : pairs0;
    gemm_bt_k<0, 64, 0, 2><<<dim3(N13 / 64, B_ / 128, 2), 256, 0, stream>>>(
        hbf, w13, nullptr, pnew, B_, N13, H_);
  }
  // tail: final(T-1)
  {
    float* pcur  = ((T_ - 1) & 1) ? pairs1 : pairs0;  // pair(9)
    float* pprev = ((T_ - 1) & 1) ? pairs0 : pairs1;  // pair(8)
    scores_k<1, 0><<<dim3(2, B_), 512, 0, stream>>>(pcur, pprev, g3p, biasc, bias13,
        encproj, full_att_w, final_w, final_b, scbuf, out_t, out_p, T_ - 1);
  }
}